// Round 8
// baseline (520.821 us; speedup 1.0000x reference)
//
#include <hip/hip_runtime.h>
#include <hip/hip_bf16.h>

#define NN 30000
#define KK 16
#define DD 128
#define ZZ 32
#define NKE (NN*KK)

typedef _Float16 h16;
typedef _Float16 half8 __attribute__((ext_vector_type(8)));
typedef float f32x4 __attribute__((ext_vector_type(4)));

// ---------------- weight fold kernel ----------------
// W'[e][d] = W[e][d] * ln_g[d];  b'[e] = b[e] + sum_d ln_b[d]*W[e][d]
struct FoldArgs {
  const float* W[4];
  const float* g[4];
  const float* bl[4];
  const float* bb[4];
};

__global__ __launch_bounds__(128) void fold_kernel(FoldArgs fa, h16* wsH, float* bpF) {
  __shared__ float red[2];
  int m = blockIdx.x >> 7;   // 0..3 : Ws1, Wn1, Ws2, Wn2
  int e = blockIdx.x & 127;
  int d = threadIdx.x;
  const float* W = fa.W[m];
  float w = W[e*DD + d];
  wsH[m*16384 + e*DD + d] = (h16)(w * fa.g[m][d]);
  float p = fa.bl[m][d] * w;
  #pragma unroll
  for (int s = 1; s < 64; s <<= 1) p += __shfl_xor(p, s);
  if ((threadIdx.x & 63) == 0) red[threadIdx.x >> 6] = p;
  __syncthreads();
  if (threadIdx.x == 0) bpF[m*DD + e] = fa.bb[m][e] + red[0] + red[1];
}

// ---------------- fused main kernel ----------------
// LDS layout (bytes)
#define SM_NBC   0         // h16[272][128] swizzled: rows 0..255 neighbor cores, 256..271 target cores
#define SM_WN    69632     // h16[128][128] swizzled (W_n' current layer)
#define SM_WS    102400    // h16[128][128] swizzled (W_s' current layer)
#define SM_SS    135168    // float[16][128] self scores
#define SM_H     143360    // float[16][128] layer output
#define SM_DW    151552    // float[16][16] dist weights
#define SM_COL   152576    // int[256] neighbor indices
#define SM_TOTAL 153600

__global__ __launch_bounds__(256, 1) void gae_main(
    const float* __restrict__ x, const int* __restrict__ edge,
    const float* __restrict__ coords,
    const float* __restrict__ lg1, const float* __restrict__ lb1,
    const float* __restrict__ lg2, const float* __restrict__ lb2,
    const h16* __restrict__ wsH, const float* __restrict__ bpF,
    const float* __restrict__ wred, const float* __restrict__ bred,
    float* __restrict__ out)
{
  extern __shared__ char sm[];
  float* ssL = (float*)(sm + SM_SS);
  float* hL  = (float*)(sm + SM_H);
  float* dwL = (float*)(sm + SM_DW);
  int*   colL = (int*)(sm + SM_COL);

  const int t   = threadIdx.x;
  const int w   = t >> 6;
  const int lane = t & 63;
  const int lr  = lane & 15;
  const int g4  = lane >> 4;
  const int blk = blockIdx.x;

  // edge_index may arrive as int32 or int64 (reference creates jnp.int64).
  // row = repeat(arange(N), 16): as true int32, word 17 == 1; as int64,
  // word 17 is the high word of row[8]==0. Block-uniform branch.
  {
    const bool e64 = (edge[17] != 1);
    colL[t] = e64 ? edge[2*NKE + 2*(blk*256 + t)] : edge[NKE + blk*256 + t];
  }
  __syncthreads();

  // ---- distance weights: thread t -> (node t>>4, k t&15) ----
  {
    int n = t >> 4;
    int c = colL[t];
    int ng = blk*16 + n;
    float2 cs = *(const float2*)(coords + 2*ng);
    float2 cn = *(const float2*)(coords + 2*c);
    float dxx = cs.x - cn.x, dyy = cs.y - cn.y;
    float dist = sqrtf(dxx*dxx + dyy*dyy);
    dwL[t] = expf(-dist * (1.0f/(1.0f + 1e-8f)));
  }

  // ---- gather + normalize neighbors, build x_agg target cores ----
  // wave w owns nodes 4w..4w+3 ; per row: lane holds cols {2*lane, 2*lane+1}
  #pragma unroll
  for (int c = 0; c < 4; ++c) {
    int node = 4*w + c;
    float ax = 0.f, ay = 0.f;
    float2 v[16];
    #pragma unroll
    for (int r = 0; r < 16; ++r) {
      int ci = colL[node*16 + r];
      v[r] = *(const float2*)(x + (long)ci*DD + 2*lane);
    }
    #pragma unroll
    for (int r = 0; r < 16; ++r) {
      float vx = v[r].x, vy = v[r].y;
      ax += vx; ay += vy;
      float s = vx + vy, q = vx*vx + vy*vy;
      #pragma unroll
      for (int m = 1; m < 64; m <<= 1) { s += __shfl_xor(s, m); q += __shfl_xor(q, m); }
      float mean = s * (1.f/128.f);
      float var  = q * (1.f/128.f) - mean*mean;
      float rs = rsqrtf(var + 1e-5f);
      union { h16 h[2]; unsigned u; } P;
      P.h[0] = (h16)((vx - mean)*rs);
      P.h[1] = (h16)((vy - mean)*rs);
      int row = node*16 + r;
      *(unsigned*)(sm + SM_NBC + row*256 + ((lane*4) ^ ((row&7)<<4))) = P.u;
    }
    // target core = LN-core of x_agg
    {
      float s = ax + ay, q = ax*ax + ay*ay;
      #pragma unroll
      for (int m = 1; m < 64; m <<= 1) { s += __shfl_xor(s, m); q += __shfl_xor(q, m); }
      float mean = s * (1.f/128.f);
      float var  = q * (1.f/128.f) - mean*mean;
      float rs = rsqrtf(var + 1e-5f);
      union { h16 h[2]; unsigned u; } P;
      P.h[0] = (h16)((ax - mean)*rs);
      P.h[1] = (h16)((ay - mean)*rs);
      int row = 256 + node;
      *(unsigned*)(sm + SM_NBC + row*256 + ((lane*4) ^ ((row&7)<<4))) = P.u;
    }
  }
  __syncthreads();

  // ---- two attention layers ----
  #pragma unroll 1
  for (int L = 0; L < 2; ++L) {
    const h16* srcS = wsH + (L ? 32768 : 0);
    const h16* srcN = wsH + (L ? 49152 : 16384);
    const float* bsP = bpF + (L ? 256 : 0);
    const float* bnP = bpF + (L ? 384 : 128);
    const float* lg = L ? lg2 : lg1;
    const float* lb = L ? lb2 : lb1;

    // stage folded weights into swizzled LDS
    #pragma unroll
    for (int i = 0; i < 8; ++i) {
      int c = i*256 + t;
      int e = c >> 4, j = c & 15;
      int dst = e*256 + ((j*16) ^ ((e&7)<<4));
      *(uint4*)(sm + SM_WN + dst) = *(const uint4*)(srcN + c*8);
      *(uint4*)(sm + SM_WS + dst) = *(const uint4*)(srcS + c*8);
    }
    __syncthreads();

    // ---- GEMM: neighbor tiles {w, w+4, w+8, w+12}; self tile E-cols {2w,2w+1} ----
    f32x4 acc[4][8];
    f32x4 accS[2];
    #pragma unroll
    for (int ii = 0; ii < 4; ++ii)
      #pragma unroll
      for (int jj = 0; jj < 8; ++jj)
        acc[ii][jj] = (f32x4){0.f,0.f,0.f,0.f};
    accS[0] = (f32x4){0.f,0.f,0.f,0.f};
    accS[1] = (f32x4){0.f,0.f,0.f,0.f};

    #pragma unroll
    for (int S = 0; S < 4; ++S) {
      const int swz = (S*64 + g4*16) ^ ((lr&7)<<4);
      half8 afr[4], bn[8], bs[2], as;
      #pragma unroll
      for (int tt = 0; tt < 4; ++tt) {
        int row = (w + 4*tt)*16 + lr;
        afr[tt] = *(const half8*)(sm + SM_NBC + row*256 + swz);
      }
      as = *(const half8*)(sm + SM_NBC + (256+lr)*256 + swz);
      #pragma unroll
      for (int E = 0; E < 8; ++E)
        bn[E] = *(const half8*)(sm + SM_WN + (E*16+lr)*256 + swz);
      #pragma unroll
      for (int j = 0; j < 2; ++j)
        bs[j] = *(const half8*)(sm + SM_WS + ((2*w+j)*16+lr)*256 + swz);
      #pragma unroll
      for (int tt = 0; tt < 4; ++tt)
        #pragma unroll
        for (int E = 0; E < 8; ++E)
          acc[tt][E] = __builtin_amdgcn_mfma_f32_16x16x32_f16(afr[tt], bn[E], acc[tt][E], 0, 0, 0);
      accS[0] = __builtin_amdgcn_mfma_f32_16x16x32_f16(as, bs[0], accS[0], 0, 0, 0);
      accS[1] = __builtin_amdgcn_mfma_f32_16x16x32_f16(as, bs[1], accS[1], 0, 0, 0);
    }

    // self scores -> LDS (C layout: col=lane&15, row=(lane>>4)*4+reg)
    #pragma unroll
    for (int j = 0; j < 2; ++j) {
      int e = (2*w+j)*16 + lr;
      float bse = bsP[e];
      #pragma unroll
      for (int r = 0; r < 4; ++r)
        ssL[(g4*4 + r)*DD + e] = accS[j][r] + bse;
    }
    __syncthreads();

    // ---- softmax + context epilogue ----
    #pragma unroll
    for (int E = 0; E < 8; ++E) {
      int e = E*16 + lr;
      float bne = bnP[e];
      float ge = lg[e], be = lb[e];
      #pragma unroll
      for (int tt = 0; tt < 4; ++tt) {
        int n = w + 4*tt;
        f32x4 sc = acc[tt][E];
        float p0 = (sc[0] + bne) * dwL[n*16 + g4*4 + 0];
        float p1 = (sc[1] + bne) * dwL[n*16 + g4*4 + 1];
        float p2 = (sc[2] + bne) * dwL[n*16 + g4*4 + 2];
        float p3 = (sc[3] + bne) * dwL[n*16 + g4*4 + 3];
        float m4 = fmaxf(fmaxf(p0,p1), fmaxf(p2,p3));
        m4 = fmaxf(m4, __shfl_xor(m4, 16));
        m4 = fmaxf(m4, __shfl_xor(m4, 32));
        float ss = ssL[n*DD + e];
        float M = fmaxf(m4, ss);
        p0 = __expf(p0 - M); p1 = __expf(p1 - M);
        p2 = __expf(p2 - M); p3 = __expf(p3 - M);
        float ps = p0+p1+p2+p3;
        ps += __shfl_xor(ps, 16);
        ps += __shfl_xor(ps, 32);
        float pself = __expf(ss - M);
        float inv = 1.0f / (ps + pself);
        // target value
        float tv = (float)*(const h16*)(sm + SM_NBC + (256+n)*256 + ((2*e) ^ ((n&7)<<4)));
        tv = tv * ge + be;
        // sum_k p_k * core_k  (4 local rows, then cross-lane)
        float part = 0.f;
        {
          int k0 = g4*4;
          float c0 = (float)*(const h16*)(sm + SM_NBC + (n*16+k0+0)*256 + ((2*e) ^ (((k0+0)&7)<<4)));
          float c1 = (float)*(const h16*)(sm + SM_NBC + (n*16+k0+1)*256 + ((2*e) ^ (((k0+1)&7)<<4)));
          float c2 = (float)*(const h16*)(sm + SM_NBC + (n*16+k0+2)*256 + ((2*e) ^ (((k0+2)&7)<<4)));
          float c3 = (float)*(const h16*)(sm + SM_NBC + (n*16+k0+3)*256 + ((2*e) ^ (((k0+3)&7)<<4)));
          part = p0*c0 + p1*c1 + p2*c2 + p3*c3;
        }
        part += __shfl_xor(part, 16);
        part += __shfl_xor(part, 32);
        float sv = ge*part + be*ps;           // sum_k p_k * (g*c_k + b)
        float ctx = 0.5f*inv*(pself*tv + sv); // beta = 1-beta = 0.5
        float hv = ctx > 0.f ? ctx : 0.01f*ctx;
        if (g4 == 0) hL[n*DD + e] = hv;
      }
    }
    __syncthreads();

    if (L == 0) {
      // normalize h1 -> new target cores (rows 256..271)
      int n = t >> 4, i = t & 15;
      float4 v0 = *(const float4*)(hL + n*DD + i*8);
      float4 v1 = *(const float4*)(hL + n*DD + i*8 + 4);
      float s = v0.x+v0.y+v0.z+v0.w + v1.x+v1.y+v1.z+v1.w;
      float q = v0.x*v0.x+v0.y*v0.y+v0.z*v0.z+v0.w*v0.w
              + v1.x*v1.x+v1.y*v1.y+v1.z*v1.z+v1.w*v1.w;
      #pragma unroll
      for (int m = 1; m < 16; m <<= 1) { s += __shfl_xor(s, m); q += __shfl_xor(q, m); }
      float mean = s*(1.f/128.f);
      float var  = q*(1.f/128.f) - mean*mean;
      float rs = rsqrtf(var + 1e-5f);
      union { h16 h[8]; uint4 u; } P;
      P.h[0] = (h16)((v0.x-mean)*rs); P.h[1] = (h16)((v0.y-mean)*rs);
      P.h[2] = (h16)((v0.z-mean)*rs); P.h[3] = (h16)((v0.w-mean)*rs);
      P.h[4] = (h16)((v1.x-mean)*rs); P.h[5] = (h16)((v1.y-mean)*rs);
      P.h[6] = (h16)((v1.z-mean)*rs); P.h[7] = (h16)((v1.w-mean)*rs);
      int row = 256 + n;
      *(uint4*)(sm + SM_NBC + row*256 + ((i*16) ^ ((n&7)<<4))) = P.u;
      __syncthreads();
    }
  }

  // ---- final projection: out = h2 @ W_red^T + b_red (f32 output) ----
  #pragma unroll
  for (int oo = 0; oo < 2; ++oo) {
    int o = t + oo*256;
    int n = o >> 5, z = o & 31;
    float acc0 = bred[z];
    #pragma unroll 8
    for (int e = 0; e < DD; ++e)
      acc0 += hL[n*DD + e] * wred[z*DD + e];
    out[(blk*16 + n)*32 + z] = acc0;
  }
}

// ---------------- launch ----------------
extern "C" void kernel_launch(void* const* d_in, const int* in_sizes, int n_in,
                              void* d_out, int out_size, void* d_ws, size_t ws_size,
                              hipStream_t stream) {
  (void)in_sizes; (void)n_in; (void)out_size; (void)ws_size;
  const float* x      = (const float*)d_in[0];
  const int*   edge   = (const int*)d_in[1];
  const float* coords = (const float*)d_in[2];
  const float* lg1v = (const float*)d_in[3];
  const float* lb1v = (const float*)d_in[4];
  const float* Ws1  = (const float*)d_in[5];
  const float* bs1  = (const float*)d_in[6];
  const float* Wn1  = (const float*)d_in[7];
  const float* bn1  = (const float*)d_in[8];
  const float* lg2v = (const float*)d_in[9];
  const float* lb2v = (const float*)d_in[10];
  const float* Ws2  = (const float*)d_in[11];
  const float* bs2  = (const float*)d_in[12];
  const float* Wn2  = (const float*)d_in[13];
  const float* bn2  = (const float*)d_in[14];
  const float* wred = (const float*)d_in[15];
  const float* bred = (const float*)d_in[16];

  h16* wsH = (h16*)d_ws;
  float* bpF = (float*)((char*)d_ws + 131072);

  FoldArgs fa;
  fa.W[0]=Ws1; fa.W[1]=Wn1; fa.W[2]=Ws2; fa.W[3]=Wn2;
  fa.g[0]=lg1v; fa.g[1]=lg1v; fa.g[2]=lg2v; fa.g[3]=lg2v;
  fa.bl[0]=lb1v; fa.bl[1]=lb1v; fa.bl[2]=lb2v; fa.bl[3]=lb2v;
  fa.bb[0]=bs1; fa.bb[1]=bn1; fa.bb[2]=bs2; fa.bb[3]=bn2;

  hipFuncSetAttribute(reinterpret_cast<const void*>(gae_main),
                      hipFuncAttributeMaxDynamicSharedMemorySize, SM_TOTAL);

  fold_kernel<<<512, 128, 0, stream>>>(fa, wsH, bpF);
  gae_main<<<1875, 256, SM_TOTAL, stream>>>(x, edge, coords, lg1v, lb1v, lg2v, lb2v,
      (const h16*)wsH, bpF, wred, bred, (float*)d_out);
}

// Round 11
// 489.909 us; speedup vs baseline: 1.0631x; 1.0631x over previous
//
#include <hip/hip_runtime.h>
#include <hip/hip_bf16.h>

#define NN 30000
#define KK 16
#define DD 128
#define ZZ 32
#define NKE (NN*KK)

typedef _Float16 h16;
typedef _Float16 half8 __attribute__((ext_vector_type(8)));
typedef float f32x4 __attribute__((ext_vector_type(4)));

// ---------------- weight fold kernel ----------------
// W'[e][d] = W[e][d] * ln_g[d];  b'[e] = b[e] + sum_d ln_b[d]*W[e][d]
struct FoldArgs {
  const float* W[4];
  const float* g[4];
  const float* bl[4];
  const float* bb[4];
};

__global__ __launch_bounds__(128) void fold_kernel(FoldArgs fa, h16* wsH, float* bpF) {
  __shared__ float red[2];
  int m = blockIdx.x >> 7;   // 0..3 : Ws1, Wn1, Ws2, Wn2
  int e = blockIdx.x & 127;
  int d = threadIdx.x;
  const float* W = fa.W[m];
  float w = W[e*DD + d];
  wsH[m*16384 + e*DD + d] = (h16)(w * fa.g[m][d]);
  float p = fa.bl[m][d] * w;
  #pragma unroll
  for (int s = 1; s < 64; s <<= 1) p += __shfl_xor(p, s);
  if ((threadIdx.x & 63) == 0) red[threadIdx.x >> 6] = p;
  __syncthreads();
  if (threadIdx.x == 0) bpF[m*DD + e] = fa.bb[m][e] + red[0] + red[1];
}

// ---------------- fused main kernel ----------------
// LDS layout (bytes) — 78 KB total -> 2 blocks/CU
#define SM_NBC   0         // h16[272][128] swizzled: rows 0..255 neighbor cores, 256..271 target cores
#define SM_SH    69632     // float[16][128]: self-scores, then (aliased) layer output h
#define SM_DW    77824     // float[16][16] dist weights
#define SM_COL   78848     // int[256] neighbor indices
#define SM_TOTAL 79872

__global__ __launch_bounds__(512, 4) void gae_main(
    const float* __restrict__ x, const int* __restrict__ edge,
    const float* __restrict__ coords,
    const float* __restrict__ lg1, const float* __restrict__ lb1,
    const float* __restrict__ lg2, const float* __restrict__ lb2,
    const h16* __restrict__ wsH, const float* __restrict__ bpF,
    const float* __restrict__ wred, const float* __restrict__ bred,
    float* __restrict__ out)
{
  extern __shared__ char sm[];
  float* shL = (float*)(sm + SM_SH);
  float* dwL = (float*)(sm + SM_DW);
  int*   colL = (int*)(sm + SM_COL);

  const int t   = threadIdx.x;
  const int w   = t >> 6;        // wave 0..7
  const int lane = t & 63;
  const int lr  = lane & 15;
  const int g4  = lane >> 4;
  const int blk = blockIdx.x;

  // edge_index may arrive as int32 or int64. row = repeat(arange(N),16):
  // as int32, word 17 == 1; as int64, word 17 is high word of 0.
  if (t < 256) {
    const bool e64 = (edge[17] != 1);
    int c = e64 ? edge[2*NKE + 2*(blk*256 + t)] : edge[NKE + blk*256 + t];
    colL[t] = c;
    // distance weights: thread t -> (node t>>4, k t&15)
    int n = t >> 4;
    int ng = blk*16 + n;
    float2 cs = *(const float2*)(coords + 2*ng);
    float2 cn = *(const float2*)(coords + 2*c);
    float dxx = cs.x - cn.x, dyy = cs.y - cn.y;
    float dist = sqrtf(dxx*dxx + dyy*dyy);
    dwL[t] = expf(-dist * (1.0f/(1.0f + 1e-8f)));
  }
  __syncthreads();

  // ---- gather + normalize neighbors; target core = LN(x_agg) ----
  // wave w owns nodes {2w, 2w+1}; per row lane holds cols {2*lane, 2*lane+1}
  #pragma unroll
  for (int c = 0; c < 2; ++c) {
    int node = 2*w + c;
    float ax = 0.f, ay = 0.f;
    float2 v[16];
    #pragma unroll
    for (int r = 0; r < 16; ++r) {
      int ci = colL[node*16 + r];
      v[r] = *(const float2*)(x + (long)ci*DD + 2*lane);
    }
    #pragma unroll
    for (int r = 0; r < 16; ++r) {
      float vx = v[r].x, vy = v[r].y;
      ax += vx; ay += vy;
      float s = vx + vy, q = vx*vx + vy*vy;
      #pragma unroll
      for (int m = 1; m < 64; m <<= 1) { s += __shfl_xor(s, m); q += __shfl_xor(q, m); }
      float mean = s * (1.f/128.f);
      float var  = q * (1.f/128.f) - mean*mean;
      float rs = rsqrtf(var + 1e-5f);
      union { h16 h[2]; unsigned u; } P;
      P.h[0] = (h16)((vx - mean)*rs);
      P.h[1] = (h16)((vy - mean)*rs);
      int row = node*16 + r;
      *(unsigned*)(sm + SM_NBC + row*256 + ((lane*4) ^ ((row&7)<<4))) = P.u;
    }
    {
      float s = ax + ay, q = ax*ax + ay*ay;
      #pragma unroll
      for (int m = 1; m < 64; m <<= 1) { s += __shfl_xor(s, m); q += __shfl_xor(q, m); }
      float mean = s * (1.f/128.f);
      float var  = q * (1.f/128.f) - mean*mean;
      float rs = rsqrtf(var + 1e-5f);
      union { h16 h[2]; unsigned u; } P;
      P.h[0] = (h16)((ax - mean)*rs);
      P.h[1] = (h16)((ay - mean)*rs);
      int row = 256 + node;
      *(unsigned*)(sm + SM_NBC + row*256 + ((lane*4) ^ ((row&7)<<4))) = P.u;
    }
  }
  __syncthreads();

  // ---- two attention layers ----
  #pragma unroll 1
  for (int L = 0; L < 2; ++L) {
    const h16* srcS = wsH + (L ? 32768 : 0);
    const h16* srcN = wsH + (L ? 49152 : 16384);
    const float* bsP = bpF + (L ? 256 : 0);
    const float* bnP = bpF + (L ? 384 : 128);
    const float* lg = L ? lg2 : lg1;
    const float* lb = L ? lb2 : lb1;

    // ---- self tile: wave w computes E-block w (cols 16w..16w+15) ----
    {
      f32x4 accS = (f32x4){0.f,0.f,0.f,0.f};
      #pragma unroll
      for (int S = 0; S < 4; ++S) {
        const int swz = (S*64 + g4*16) ^ ((lr&7)<<4);
        half8 as = *(const half8*)(sm + SM_NBC + (256+lr)*256 + swz);
        half8 bs = *(const half8*)(srcS + (w*16+lr)*128 + S*32 + g4*8);
        accS = __builtin_amdgcn_mfma_f32_16x16x32_f16(as, bs, accS, 0, 0, 0);
      }
      float bse = bsP[w*16 + lr];
      #pragma unroll
      for (int r = 0; r < 4; ++r)
        shL[(g4*4 + r)*DD + w*16 + lr] = accS[r] + bse;   // self score[node][e]
    }
    __syncthreads();

    // ---- neighbor tiles {w, w+8}; E split in two halves (reg pressure) ----
    #pragma unroll
    for (int half = 0; half < 2; ++half) {
      f32x4 acc[2][4];
      #pragma unroll
      for (int ii = 0; ii < 2; ++ii)
        #pragma unroll
        for (int jj = 0; jj < 4; ++jj)
          acc[ii][jj] = (f32x4){0.f,0.f,0.f,0.f};

      #pragma unroll
      for (int S = 0; S < 4; ++S) {
        const int swz = (S*64 + g4*16) ^ ((lr&7)<<4);
        half8 a0 = *(const half8*)(sm + SM_NBC + ((w    )*16+lr)*256 + swz);
        half8 a1 = *(const half8*)(sm + SM_NBC + ((w + 8)*16+lr)*256 + swz);
        half8 bn[4];
        #pragma unroll
        for (int E = 0; E < 4; ++E)
          bn[E] = *(const half8*)(srcN + ((half*4+E)*16+lr)*128 + S*32 + g4*8);
        #pragma unroll
        for (int E = 0; E < 4; ++E) {
          acc[0][E] = __builtin_amdgcn_mfma_f32_16x16x32_f16(a0, bn[E], acc[0][E], 0, 0, 0);
          acc[1][E] = __builtin_amdgcn_mfma_f32_16x16x32_f16(a1, bn[E], acc[1][E], 0, 0, 0);
        }
      }

      // ---- softmax + context epilogue for these 4 E-blocks ----
      #pragma unroll
      for (int E = 0; E < 4; ++E) {
        int e = (half*4 + E)*16 + lr;
        float bne = bnP[e];
        float ge = lg[e], be = lb[e];
        #pragma unroll
        for (int tt = 0; tt < 2; ++tt) {
          int n = w + 8*tt;
          f32x4 sc = acc[tt][E];
          float p0 = (sc[0] + bne) * dwL[n*16 + g4*4 + 0];
          float p1 = (sc[1] + bne) * dwL[n*16 + g4*4 + 1];
          float p2 = (sc[2] + bne) * dwL[n*16 + g4*4 + 2];
          float p3 = (sc[3] + bne) * dwL[n*16 + g4*4 + 3];
          float m4 = fmaxf(fmaxf(p0,p1), fmaxf(p2,p3));
          m4 = fmaxf(m4, __shfl_xor(m4, 16));
          m4 = fmaxf(m4, __shfl_xor(m4, 32));
          float ss = shL[n*DD + e];
          float M = fmaxf(m4, ss);
          p0 = __expf(p0 - M); p1 = __expf(p1 - M);
          p2 = __expf(p2 - M); p3 = __expf(p3 - M);
          float ps = p0+p1+p2+p3;
          ps += __shfl_xor(ps, 16);
          ps += __shfl_xor(ps, 32);
          float pself = __expf(ss - M);
          float inv = 1.0f / (ps + pself);
          float tv = (float)*(const h16*)(sm + SM_NBC + (256+n)*256 + ((2*e) ^ ((n&7)<<4)));
          tv = tv * ge + be;
          float part;
          {
            int k0 = g4*4;
            float c0 = (float)*(const h16*)(sm + SM_NBC + (n*16+k0+0)*256 + ((2*e) ^ (((k0+0)&7)<<4)));
            float c1 = (float)*(const h16*)(sm + SM_NBC + (n*16+k0+1)*256 + ((2*e) ^ (((k0+1)&7)<<4)));
            float c2 = (float)*(const h16*)(sm + SM_NBC + (n*16+k0+2)*256 + ((2*e) ^ (((k0+2)&7)<<4)));
            float c3 = (float)*(const h16*)(sm + SM_NBC + (n*16+k0+3)*256 + ((2*e) ^ (((k0+3)&7)<<4)));
            part = p0*c0 + p1*c1 + p2*c2 + p3*c3;
          }
          part += __shfl_xor(part, 16);
          part += __shfl_xor(part, 32);
          float sv = ge*part + be*ps;           // sum_k p_k * (g*c_k + b)
          float ctx = 0.5f*inv*(pself*tv + sv); // beta = 1-beta = 0.5
          float hv = ctx > 0.f ? ctx : 0.01f*ctx;
          if (g4 == 0) shL[n*DD + e] = hv;      // overwrite score with h (read-before-write in-lane)
        }
      }
    }
    __syncthreads();

    if (L == 0) {
      // normalize h1 -> new target cores (rows 256..271); 32 lanes per node
      int n = t >> 5, i = t & 31;
      float4 v0 = *(const float4*)(shL + n*DD + i*4);
      float s = v0.x+v0.y+v0.z+v0.w;
      float q = v0.x*v0.x+v0.y*v0.y+v0.z*v0.z+v0.w*v0.w;
      #pragma unroll
      for (int m = 1; m < 32; m <<= 1) { s += __shfl_xor(s, m); q += __shfl_xor(q, m); }
      float mean = s*(1.f/128.f);
      float var  = q*(1.f/128.f) - mean*mean;
      float rs = rsqrtf(var + 1e-5f);
      union { h16 h[4]; uint2 u; } P;
      P.h[0] = (h16)((v0.x-mean)*rs); P.h[1] = (h16)((v0.y-mean)*rs);
      P.h[2] = (h16)((v0.z-mean)*rs); P.h[3] = (h16)((v0.w-mean)*rs);
      int row = 256 + n;
      *(uint2*)(sm + SM_NBC + row*256 + ((i*8) ^ ((n&7)<<4))) = P.u;
      __syncthreads();
    }
  }

  // ---- final projection: out = h2 @ W_red^T + b_red (f32 output) ----
  {
    int n = t >> 5, z = t & 31;
    float acc0 = bred[z];
    #pragma unroll 8
    for (int e4 = 0; e4 < 32; ++e4) {
      float4 hv = *(const float4*)(shL + n*DD + e4*4);
      float4 wv = *(const float4*)(wred + z*DD + e4*4);
      acc0 += hv.x*wv.x + hv.y*wv.y + hv.z*wv.z + hv.w*wv.w;
    }
    out[(blk*16 + n)*32 + z] = acc0;
  }
}

// ---------------- launch ----------------
extern "C" void kernel_launch(void* const* d_in, const int* in_sizes, int n_in,
                              void* d_out, int out_size, void* d_ws, size_t ws_size,
                              hipStream_t stream) {
  (void)in_sizes; (void)n_in; (void)out_size; (void)ws_size;
  const float* x      = (const float*)d_in[0];
  const int*   edge   = (const int*)d_in[1];
  const float* coords = (const float*)d_in[2];
  const float* lg1v = (const float*)d_in[3];
  const float* lb1v = (const float*)d_in[4];
  const float* Ws1  = (const float*)d_in[5];
  const float* bs1  = (const float*)d_in[6];
  const float* Wn1  = (const float*)d_in[7];
  const float* bn1  = (const float*)d_in[8];
  const float* lg2v = (const float*)d_in[9];
  const float* lb2v = (const float*)d_in[10];
  const float* Ws2  = (const float*)d_in[11];
  const float* bs2  = (const float*)d_in[12];
  const float* Wn2  = (const float*)d_in[13];
  const float* bn2  = (const float*)d_in[14];
  const float* wred = (const float*)d_in[15];
  const float* bred = (const float*)d_in[16];

  h16* wsH = (h16*)d_ws;
  float* bpF = (float*)((char*)d_ws + 131072);

  FoldArgs fa;
  fa.W[0]=Ws1; fa.W[1]=Wn1; fa.W[2]=Ws2; fa.W[3]=Wn2;
  fa.g[0]=lg1v; fa.g[1]=lg1v; fa.g[2]=lg2v; fa.g[3]=lg2v;
  fa.bl[0]=lb1v; fa.bl[1]=lb1v; fa.bl[2]=lb2v; fa.bl[3]=lb2v;
  fa.bb[0]=bs1; fa.bb[1]=bn1; fa.bb[2]=bs2; fa.bb[3]=bn2;

  hipFuncSetAttribute(reinterpret_cast<const void*>(gae_main),
                      hipFuncAttributeMaxDynamicSharedMemorySize, SM_TOTAL);

  fold_kernel<<<512, 128, 0, stream>>>(fa, wsH, bpF);
  gae_main<<<1875, 512, SM_TOTAL, stream>>>(x, edge, coords, lg1v, lb1v, lg2v, lb2v,
      (const h16*)wsH, bpF, wred, bred, (float*)d_out);
}

// Round 12
// 488.598 us; speedup vs baseline: 1.0659x; 1.0027x over previous
//
#include <hip/hip_runtime.h>
#include <hip/hip_bf16.h>

#define NN 30000
#define KK 16
#define DD 128
#define ZZ 32
#define NKE (NN*KK)

typedef _Float16 h16;
typedef _Float16 half8 __attribute__((ext_vector_type(8)));
typedef float f32x4 __attribute__((ext_vector_type(4)));

// ---------------- weight fold kernel ----------------
// W'[e][d] = W[e][d] * ln_g[d];  b'[e] = b[e] + sum_d ln_b[d]*W[e][d]
struct FoldArgs {
  const float* W[4];
  const float* g[4];
  const float* bl[4];
  const float* bb[4];
};

__global__ __launch_bounds__(128) void fold_kernel(FoldArgs fa, h16* wsH, float* bpF) {
  __shared__ float red[2];
  int m = blockIdx.x >> 7;   // 0..3 : Ws1, Wn1, Ws2, Wn2
  int e = blockIdx.x & 127;
  int d = threadIdx.x;
  const float* W = fa.W[m];
  float w = W[e*DD + d];
  wsH[m*16384 + e*DD + d] = (h16)(w * fa.g[m][d]);
  float p = fa.bl[m][d] * w;
  #pragma unroll
  for (int s = 1; s < 64; s <<= 1) p += __shfl_xor(p, s);
  if ((threadIdx.x & 63) == 0) red[threadIdx.x >> 6] = p;
  __syncthreads();
  if (threadIdx.x == 0) bpF[m*DD + e] = fa.bb[m][e] + red[0] + red[1];
}

// ---------------- fused main kernel ----------------
// LDS layout (bytes) — 78 KB total -> 2 blocks/CU (= 16 waves/CU = 4 waves/EU)
#define SM_NBC   0         // h16[272][128] swizzled: rows 0..255 neighbor cores, 256..271 target cores
#define SM_SH    69632     // float[16][128]: self-scores, then (aliased) layer output h
#define SM_DW    77824     // float[16][16] dist weights
#define SM_COL   78848     // int[256] neighbor indices
#define SM_TOTAL 79872

// waves_per_eu pinned to (4,4): LDS already caps us at 2 blocks/CU = 4 waves/EU,
// so give the register allocator the full 512/4 = 128 VGPR budget and forbid the
// 8-wave/64-VGPR squeeze that spilled 500 MB of scratch through HBM in round 11.
__global__ __launch_bounds__(512) __attribute__((amdgpu_waves_per_eu(4, 4)))
void gae_main(
    const float* __restrict__ x, const int* __restrict__ edge,
    const float* __restrict__ coords,
    const float* __restrict__ lg1, const float* __restrict__ lb1,
    const float* __restrict__ lg2, const float* __restrict__ lb2,
    const h16* __restrict__ wsH, const float* __restrict__ bpF,
    const float* __restrict__ wred, const float* __restrict__ bred,
    float* __restrict__ out)
{
  extern __shared__ char sm[];
  float* shL = (float*)(sm + SM_SH);
  float* dwL = (float*)(sm + SM_DW);
  int*   colL = (int*)(sm + SM_COL);

  const int t   = threadIdx.x;
  const int w   = t >> 6;        // wave 0..7
  const int lane = t & 63;
  const int lr  = lane & 15;
  const int g4  = lane >> 4;
  const int blk = blockIdx.x;

  // edge_index may arrive as int32 or int64. row = repeat(arange(N),16):
  // as int32, word 17 == 1; as int64, word 17 is high word of 0.
  if (t < 256) {
    const bool e64 = (edge[17] != 1);
    int c = e64 ? edge[2*NKE + 2*(blk*256 + t)] : edge[NKE + blk*256 + t];
    colL[t] = c;
    // distance weights: thread t -> (node t>>4, k t&15)
    int n = t >> 4;
    int ng = blk*16 + n;
    float2 cs = *(const float2*)(coords + 2*ng);
    float2 cn = *(const float2*)(coords + 2*c);
    float dxx = cs.x - cn.x, dyy = cs.y - cn.y;
    float dist = sqrtf(dxx*dxx + dyy*dyy);
    dwL[t] = expf(-dist * (1.0f/(1.0f + 1e-8f)));
  }
  __syncthreads();

  // ---- gather + normalize neighbors; target core = LN(x_agg) ----
  // wave w owns nodes {2w, 2w+1}; per row lane holds cols {2*lane, 2*lane+1}
  #pragma unroll
  for (int c = 0; c < 2; ++c) {
    int node = 2*w + c;
    float ax = 0.f, ay = 0.f;
    float2 v[16];
    #pragma unroll
    for (int r = 0; r < 16; ++r) {
      int ci = colL[node*16 + r];
      v[r] = *(const float2*)(x + (long)ci*DD + 2*lane);
    }
    #pragma unroll
    for (int r = 0; r < 16; ++r) {
      float vx = v[r].x, vy = v[r].y;
      ax += vx; ay += vy;
      float s = vx + vy, q = vx*vx + vy*vy;
      #pragma unroll
      for (int m = 1; m < 64; m <<= 1) { s += __shfl_xor(s, m); q += __shfl_xor(q, m); }
      float mean = s * (1.f/128.f);
      float var  = q * (1.f/128.f) - mean*mean;
      float rs = rsqrtf(var + 1e-5f);
      union { h16 h[2]; unsigned u; } P;
      P.h[0] = (h16)((vx - mean)*rs);
      P.h[1] = (h16)((vy - mean)*rs);
      int row = node*16 + r;
      *(unsigned*)(sm + SM_NBC + row*256 + ((lane*4) ^ ((row&7)<<4))) = P.u;
    }
    {
      float s = ax + ay, q = ax*ax + ay*ay;
      #pragma unroll
      for (int m = 1; m < 64; m <<= 1) { s += __shfl_xor(s, m); q += __shfl_xor(q, m); }
      float mean = s * (1.f/128.f);
      float var  = q * (1.f/128.f) - mean*mean;
      float rs = rsqrtf(var + 1e-5f);
      union { h16 h[2]; unsigned u; } P;
      P.h[0] = (h16)((ax - mean)*rs);
      P.h[1] = (h16)((ay - mean)*rs);
      int row = 256 + node;
      *(unsigned*)(sm + SM_NBC + row*256 + ((lane*4) ^ ((row&7)<<4))) = P.u;
    }
  }
  __syncthreads();

  // ---- two attention layers ----
  #pragma unroll 1
  for (int L = 0; L < 2; ++L) {
    const h16* srcS = wsH + (L ? 32768 : 0);
    const h16* srcN = wsH + (L ? 49152 : 16384);
    const float* bsP = bpF + (L ? 256 : 0);
    const float* bnP = bpF + (L ? 384 : 128);
    const float* lg = L ? lg2 : lg1;
    const float* lb = L ? lb2 : lb1;

    // ---- self tile: wave w computes E-block w (cols 16w..16w+15) ----
    {
      f32x4 accS = (f32x4){0.f,0.f,0.f,0.f};
      #pragma unroll
      for (int S = 0; S < 4; ++S) {
        const int swz = (S*64 + g4*16) ^ ((lr&7)<<4);
        half8 as = *(const half8*)(sm + SM_NBC + (256+lr)*256 + swz);
        half8 bs = *(const half8*)(srcS + (w*16+lr)*128 + S*32 + g4*8);
        accS = __builtin_amdgcn_mfma_f32_16x16x32_f16(as, bs, accS, 0, 0, 0);
      }
      float bse = bsP[w*16 + lr];
      #pragma unroll
      for (int r = 0; r < 4; ++r)
        shL[(g4*4 + r)*DD + w*16 + lr] = accS[r] + bse;   // self score[node][e]
    }
    __syncthreads();

    // ---- neighbor tiles {w, w+8}; E split in two halves (reg pressure) ----
    #pragma unroll
    for (int half = 0; half < 2; ++half) {
      f32x4 acc[2][4];
      #pragma unroll
      for (int ii = 0; ii < 2; ++ii)
        #pragma unroll
        for (int jj = 0; jj < 4; ++jj)
          acc[ii][jj] = (f32x4){0.f,0.f,0.f,0.f};

      #pragma unroll
      for (int S = 0; S < 4; ++S) {
        const int swz = (S*64 + g4*16) ^ ((lr&7)<<4);
        half8 a0 = *(const half8*)(sm + SM_NBC + ((w    )*16+lr)*256 + swz);
        half8 a1 = *(const half8*)(sm + SM_NBC + ((w + 8)*16+lr)*256 + swz);
        half8 bn[4];
        #pragma unroll
        for (int E = 0; E < 4; ++E)
          bn[E] = *(const half8*)(srcN + ((half*4+E)*16+lr)*128 + S*32 + g4*8);
        #pragma unroll
        for (int E = 0; E < 4; ++E) {
          acc[0][E] = __builtin_amdgcn_mfma_f32_16x16x32_f16(a0, bn[E], acc[0][E], 0, 0, 0);
          acc[1][E] = __builtin_amdgcn_mfma_f32_16x16x32_f16(a1, bn[E], acc[1][E], 0, 0, 0);
        }
      }

      // ---- softmax + context epilogue for these 4 E-blocks ----
      #pragma unroll
      for (int E = 0; E < 4; ++E) {
        int e = (half*4 + E)*16 + lr;
        float bne = bnP[e];
        float ge = lg[e], be = lb[e];
        #pragma unroll
        for (int tt = 0; tt < 2; ++tt) {
          int n = w + 8*tt;
          f32x4 sc = acc[tt][E];
          float p0 = (sc[0] + bne) * dwL[n*16 + g4*4 + 0];
          float p1 = (sc[1] + bne) * dwL[n*16 + g4*4 + 1];
          float p2 = (sc[2] + bne) * dwL[n*16 + g4*4 + 2];
          float p3 = (sc[3] + bne) * dwL[n*16 + g4*4 + 3];
          float m4 = fmaxf(fmaxf(p0,p1), fmaxf(p2,p3));
          m4 = fmaxf(m4, __shfl_xor(m4, 16));
          m4 = fmaxf(m4, __shfl_xor(m4, 32));
          float ss = shL[n*DD + e];
          float M = fmaxf(m4, ss);
          p0 = __expf(p0 - M); p1 = __expf(p1 - M);
          p2 = __expf(p2 - M); p3 = __expf(p3 - M);
          float ps = p0+p1+p2+p3;
          ps += __shfl_xor(ps, 16);
          ps += __shfl_xor(ps, 32);
          float pself = __expf(ss - M);
          float inv = 1.0f / (ps + pself);
          float tv = (float)*(const h16*)(sm + SM_NBC + (256+n)*256 + ((2*e) ^ ((n&7)<<4)));
          tv = tv * ge + be;
          float part;
          {
            int k0 = g4*4;
            float c0 = (float)*(const h16*)(sm + SM_NBC + (n*16+k0+0)*256 + ((2*e) ^ (((k0+0)&7)<<4)));
            float c1 = (float)*(const h16*)(sm + SM_NBC + (n*16+k0+1)*256 + ((2*e) ^ (((k0+1)&7)<<4)));
            float c2 = (float)*(const h16*)(sm + SM_NBC + (n*16+k0+2)*256 + ((2*e) ^ (((k0+2)&7)<<4)));
            float c3 = (float)*(const h16*)(sm + SM_NBC + (n*16+k0+3)*256 + ((2*e) ^ (((k0+3)&7)<<4)));
            part = p0*c0 + p1*c1 + p2*c2 + p3*c3;
          }
          part += __shfl_xor(part, 16);
          part += __shfl_xor(part, 32);
          float sv = ge*part + be*ps;           // sum_k p_k * (g*c_k + b)
          float ctx = 0.5f*inv*(pself*tv + sv); // beta = 1-beta = 0.5
          float hv = ctx > 0.f ? ctx : 0.01f*ctx;
          if (g4 == 0) shL[n*DD + e] = hv;      // overwrite score with h (read-before-write in-lane)
        }
      }
    }
    __syncthreads();

    if (L == 0) {
      // normalize h1 -> new target cores (rows 256..271); 32 lanes per node
      int n = t >> 5, i = t & 31;
      float4 v0 = *(const float4*)(shL + n*DD + i*4);
      float s = v0.x+v0.y+v0.z+v0.w;
      float q = v0.x*v0.x+v0.y*v0.y+v0.z*v0.z+v0.w*v0.w;
      #pragma unroll
      for (int m = 1; m < 32; m <<= 1) { s += __shfl_xor(s, m); q += __shfl_xor(q, m); }
      float mean = s*(1.f/128.f);
      float var  = q*(1.f/128.f) - mean*mean;
      float rs = rsqrtf(var + 1e-5f);
      union { h16 h[4]; uint2 u; } P;
      P.h[0] = (h16)((v0.x-mean)*rs); P.h[1] = (h16)((v0.y-mean)*rs);
      P.h[2] = (h16)((v0.z-mean)*rs); P.h[3] = (h16)((v0.w-mean)*rs);
      int row = 256 + n;
      *(uint2*)(sm + SM_NBC + row*256 + ((i*8) ^ ((n&7)<<4))) = P.u;
      __syncthreads();
    }
  }

  // ---- final projection: out = h2 @ W_red^T + b_red (f32 output) ----
  {
    int n = t >> 5, z = t & 31;
    float acc0 = bred[z];
    #pragma unroll 8
    for (int e4 = 0; e4 < 32; ++e4) {
      float4 hv = *(const float4*)(shL + n*DD + e4*4);
      float4 wv = *(const float4*)(wred + z*DD + e4*4);
      acc0 += hv.x*wv.x + hv.y*wv.y + hv.z*wv.z + hv.w*wv.w;
    }
    out[(blk*16 + n)*32 + z] = acc0;
  }
}

// ---------------- launch ----------------
extern "C" void kernel_launch(void* const* d_in, const int* in_sizes, int n_in,
                              void* d_out, int out_size, void* d_ws, size_t ws_size,
                              hipStream_t stream) {
  (void)in_sizes; (void)n_in; (void)out_size; (void)ws_size;
  const float* x      = (const float*)d_in[0];
  const int*   edge   = (const int*)d_in[1];
  const float* coords = (const float*)d_in[2];
  const float* lg1v = (const float*)d_in[3];
  const float* lb1v = (const float*)d_in[4];
  const float* Ws1  = (const float*)d_in[5];
  const float* bs1  = (const float*)d_in[6];
  const float* Wn1  = (const float*)d_in[7];
  const float* bn1  = (const float*)d_in[8];
  const float* lg2v = (const float*)d_in[9];
  const float* lb2v = (const float*)d_in[10];
  const float* Ws2  = (const float*)d_in[11];
  const float* bs2  = (const float*)d_in[12];
  const float* Wn2  = (const float*)d_in[13];
  const float* bn2  = (const float*)d_in[14];
  const float* wred = (const float*)d_in[15];
  const float* bred = (const float*)d_in[16];

  h16* wsH = (h16*)d_ws;
  float* bpF = (float*)((char*)d_ws + 131072);

  FoldArgs fa;
  fa.W[0]=Ws1; fa.W[1]=Wn1; fa.W[2]=Ws2; fa.W[3]=Wn2;
  fa.g[0]=lg1v; fa.g[1]=lg1v; fa.g[2]=lg2v; fa.g[3]=lg2v;
  fa.bl[0]=lb1v; fa.bl[1]=lb1v; fa.bl[2]=lb2v; fa.bl[3]=lb2v;
  fa.bb[0]=bs1; fa.bb[1]=bn1; fa.bb[2]=bs2; fa.bb[3]=bn2;

  hipFuncSetAttribute(reinterpret_cast<const void*>(gae_main),
                      hipFuncAttributeMaxDynamicSharedMemorySize, SM_TOTAL);

  fold_kernel<<<512, 128, 0, stream>>>(fa, wsH, bpF);
  gae_main<<<1875, 512, SM_TOTAL, stream>>>(x, edge, coords, lg1v, lb1v, lg2v, lb2v,
      (const h16*)wsH, bpF, wred, bred, (float*)d_out);
}

// Round 14
// 382.815 us; speedup vs baseline: 1.3605x; 1.2763x over previous
//
#include <hip/hip_runtime.h>
#include <hip/hip_bf16.h>

#define NN 30000
#define KK 16
#define DD 128
#define ZZ 32
#define NKE (NN*KK)

typedef _Float16 h16;
typedef _Float16 half8 __attribute__((ext_vector_type(8)));
typedef float f32x4 __attribute__((ext_vector_type(4)));

// ---------------- weight fold kernel ----------------
// W'[e][d] = W[e][d] * ln_g[d];  b'[e] = b[e] + sum_d ln_b[d]*W[e][d]
struct FoldArgs {
  const float* W[4];
  const float* g[4];
  const float* bl[4];
  const float* bb[4];
};

__global__ __launch_bounds__(128) void fold_kernel(FoldArgs fa, h16* wsH, float* bpF) {
  __shared__ float red[2];
  int m = blockIdx.x >> 7;   // 0..3 : Ws1, Wn1, Ws2, Wn2
  int e = blockIdx.x & 127;
  int d = threadIdx.x;
  const float* W = fa.W[m];
  float w = W[e*DD + d];
  wsH[m*16384 + e*DD + d] = (h16)(w * fa.g[m][d]);
  float p = fa.bl[m][d] * w;
  #pragma unroll
  for (int s = 1; s < 64; s <<= 1) p += __shfl_xor(p, s);
  if ((threadIdx.x & 63) == 0) red[threadIdx.x >> 6] = p;
  __syncthreads();
  if (threadIdx.x == 0) bpF[m*DD + e] = fa.bb[m][e] + red[0] + red[1];
}

// ---------------- fused main kernel ----------------
// STATIC LDS (78 KB) so the compiler KNOWS occupancy is LDS-capped at
// 2 blocks/CU = 4 waves/EU and budgets 128 VGPRs instead of assuming
// 8 waves/EU (dynamic-LDS blind spot) and spilling 500 MB of scratch
// through HBM (rounds 11/12: WRITE_SIZE 255 MB vs 3.84 MB of output).
struct SmemT {
  char  nbc[69632];      // h16[272][128] swizzled: 0..255 neighbor cores, 256..271 target cores
  float sh[16*128];      // self-scores, then (aliased) layer output h
  float dw[256];         // dist weights [16][16]
  int   col[256];        // neighbor indices
};

__global__ __launch_bounds__(512, 4) void gae_main(
    const float* __restrict__ x, const int* __restrict__ edge,
    const float* __restrict__ coords,
    const float* __restrict__ lg1, const float* __restrict__ lb1,
    const float* __restrict__ lg2, const float* __restrict__ lb2,
    const h16* __restrict__ wsH, const float* __restrict__ bpF,
    const float* __restrict__ wred, const float* __restrict__ bred,
    float* __restrict__ out)
{
  __shared__ SmemT smem;
  char*  nbcL = smem.nbc;
  float* shL  = smem.sh;
  float* dwL  = smem.dw;
  int*   colL = smem.col;

  const int t   = threadIdx.x;
  const int w   = t >> 6;        // wave 0..7
  const int lane = t & 63;
  const int lr  = lane & 15;
  const int g4  = lane >> 4;
  const int blk = blockIdx.x;

  // edge_index may arrive as int32 or int64. row = repeat(arange(N),16):
  // as int32, word 17 == 1; as int64, word 17 is high word of 0.
  if (t < 256) {
    const bool e64 = (edge[17] != 1);
    int c = e64 ? edge[2*NKE + 2*(blk*256 + t)] : edge[NKE + blk*256 + t];
    colL[t] = c;
    // distance weights: thread t -> (node t>>4, k t&15)
    int n = t >> 4;
    int ng = blk*16 + n;
    float2 cs = *(const float2*)(coords + 2*ng);
    float2 cn = *(const float2*)(coords + 2*c);
    float dxx = cs.x - cn.x, dyy = cs.y - cn.y;
    float dist = sqrtf(dxx*dxx + dyy*dyy);
    dwL[t] = expf(-dist * (1.0f/(1.0f + 1e-8f)));
  }
  __syncthreads();

  // ---- gather + normalize neighbors; target core = LN(x_agg) ----
  // wave w owns nodes {2w, 2w+1}; per row lane holds cols {2*lane, 2*lane+1}.
  // Gather in 2 batches of 8 rows to halve staged-register pressure.
  #pragma unroll 1
  for (int c = 0; c < 2; ++c) {
    int node = 2*w + c;
    float ax = 0.f, ay = 0.f;
    #pragma unroll 1
    for (int b = 0; b < 2; ++b) {
      float2 v[8];
      #pragma unroll
      for (int r = 0; r < 8; ++r) {
        int ci = colL[node*16 + b*8 + r];
        v[r] = *(const float2*)(x + (long)ci*DD + 2*lane);
      }
      #pragma unroll
      for (int r = 0; r < 8; ++r) {
        float vx = v[r].x, vy = v[r].y;
        ax += vx; ay += vy;
        float s = vx + vy, q = vx*vx + vy*vy;
        #pragma unroll
        for (int m = 1; m < 64; m <<= 1) { s += __shfl_xor(s, m); q += __shfl_xor(q, m); }
        float mean = s * (1.f/128.f);
        float var  = q * (1.f/128.f) - mean*mean;
        float rs = rsqrtf(var + 1e-5f);
        union { h16 h[2]; unsigned u; } P;
        P.h[0] = (h16)((vx - mean)*rs);
        P.h[1] = (h16)((vy - mean)*rs);
        int row = node*16 + b*8 + r;
        *(unsigned*)(nbcL + row*256 + ((lane*4) ^ ((row&7)<<4))) = P.u;
      }
    }
    {
      float s = ax + ay, q = ax*ax + ay*ay;
      #pragma unroll
      for (int m = 1; m < 64; m <<= 1) { s += __shfl_xor(s, m); q += __shfl_xor(q, m); }
      float mean = s * (1.f/128.f);
      float var  = q * (1.f/128.f) - mean*mean;
      float rs = rsqrtf(var + 1e-5f);
      union { h16 h[2]; unsigned u; } P;
      P.h[0] = (h16)((ax - mean)*rs);
      P.h[1] = (h16)((ay - mean)*rs);
      int row = 256 + node;
      *(unsigned*)(nbcL + row*256 + ((lane*4) ^ ((row&7)<<4))) = P.u;
    }
  }
  __syncthreads();

  // ---- two attention layers ----
  #pragma unroll 1
  for (int L = 0; L < 2; ++L) {
    const h16* srcS = wsH + (L ? 32768 : 0);
    const h16* srcN = wsH + (L ? 49152 : 16384);
    const float* bsP = bpF + (L ? 256 : 0);
    const float* bnP = bpF + (L ? 384 : 128);
    const float* lg = L ? lg2 : lg1;
    const float* lb = L ? lb2 : lb1;

    // ---- self tile: wave w computes E-block w (cols 16w..16w+15) ----
    {
      f32x4 accS = (f32x4){0.f,0.f,0.f,0.f};
      #pragma unroll
      for (int S = 0; S < 4; ++S) {
        const int swz = (S*64 + g4*16) ^ ((lr&7)<<4);
        half8 as = *(const half8*)(nbcL + (256+lr)*256 + swz);
        half8 bs = *(const half8*)(srcS + (w*16+lr)*128 + S*32 + g4*8);
        accS = __builtin_amdgcn_mfma_f32_16x16x32_f16(as, bs, accS, 0, 0, 0);
      }
      float bse = bsP[w*16 + lr];
      #pragma unroll
      for (int r = 0; r < 4; ++r)
        shL[(g4*4 + r)*DD + w*16 + lr] = accS[r] + bse;   // self score[node][e]
    }
    __syncthreads();

    // ---- neighbor tiles {w, w+8}; E split in two halves, SERIAL (reg pressure) ----
    #pragma unroll 1
    for (int half = 0; half < 2; ++half) {
      f32x4 acc[2][4];
      #pragma unroll
      for (int ii = 0; ii < 2; ++ii)
        #pragma unroll
        for (int jj = 0; jj < 4; ++jj)
          acc[ii][jj] = (f32x4){0.f,0.f,0.f,0.f};

      #pragma unroll
      for (int S = 0; S < 4; ++S) {
        const int swz = (S*64 + g4*16) ^ ((lr&7)<<4);
        half8 a0 = *(const half8*)(nbcL + ((w    )*16+lr)*256 + swz);
        half8 a1 = *(const half8*)(nbcL + ((w + 8)*16+lr)*256 + swz);
        half8 bn[4];
        #pragma unroll
        for (int E = 0; E < 4; ++E)
          bn[E] = *(const half8*)(srcN + ((half*4+E)*16+lr)*128 + S*32 + g4*8);
        #pragma unroll
        for (int E = 0; E < 4; ++E) {
          acc[0][E] = __builtin_amdgcn_mfma_f32_16x16x32_f16(a0, bn[E], acc[0][E], 0, 0, 0);
          acc[1][E] = __builtin_amdgcn_mfma_f32_16x16x32_f16(a1, bn[E], acc[1][E], 0, 0, 0);
        }
      }

      // ---- softmax + context epilogue for these 4 E-blocks ----
      #pragma unroll
      for (int E = 0; E < 4; ++E) {
        int e = (half*4 + E)*16 + lr;
        float bne = bnP[e];
        float ge = lg[e], be = lb[e];
        #pragma unroll
        for (int tt = 0; tt < 2; ++tt) {
          int n = w + 8*tt;
          f32x4 sc = acc[tt][E];
          float p0 = (sc[0] + bne) * dwL[n*16 + g4*4 + 0];
          float p1 = (sc[1] + bne) * dwL[n*16 + g4*4 + 1];
          float p2 = (sc[2] + bne) * dwL[n*16 + g4*4 + 2];
          float p3 = (sc[3] + bne) * dwL[n*16 + g4*4 + 3];
          float m4 = fmaxf(fmaxf(p0,p1), fmaxf(p2,p3));
          m4 = fmaxf(m4, __shfl_xor(m4, 16));
          m4 = fmaxf(m4, __shfl_xor(m4, 32));
          float ss = shL[n*DD + e];
          float M = fmaxf(m4, ss);
          p0 = __expf(p0 - M); p1 = __expf(p1 - M);
          p2 = __expf(p2 - M); p3 = __expf(p3 - M);
          float ps = p0+p1+p2+p3;
          ps += __shfl_xor(ps, 16);
          ps += __shfl_xor(ps, 32);
          float pself = __expf(ss - M);
          float inv = 1.0f / (ps + pself);
          float tv = (float)*(const h16*)(nbcL + (256+n)*256 + ((2*e) ^ ((n&7)<<4)));
          tv = tv * ge + be;
          float part;
          {
            int k0 = g4*4;
            float c0 = (float)*(const h16*)(nbcL + (n*16+k0+0)*256 + ((2*e) ^ (((k0+0)&7)<<4)));
            float c1 = (float)*(const h16*)(nbcL + (n*16+k0+1)*256 + ((2*e) ^ (((k0+1)&7)<<4)));
            float c2 = (float)*(const h16*)(nbcL + (n*16+k0+2)*256 + ((2*e) ^ (((k0+2)&7)<<4)));
            float c3 = (float)*(const h16*)(nbcL + (n*16+k0+3)*256 + ((2*e) ^ (((k0+3)&7)<<4)));
            part = p0*c0 + p1*c1 + p2*c2 + p3*c3;
          }
          part += __shfl_xor(part, 16);
          part += __shfl_xor(part, 32);
          float sv = ge*part + be*ps;           // sum_k p_k * (g*c_k + b)
          float ctx = 0.5f*inv*(pself*tv + sv); // beta = 1-beta = 0.5
          float hv = ctx > 0.f ? ctx : 0.01f*ctx;
          if (g4 == 0) shL[n*DD + e] = hv;      // overwrite score with h (read-before-write in-lane)
        }
      }
    }
    __syncthreads();

    if (L == 0) {
      // normalize h1 -> new target cores (rows 256..271); 32 lanes per node
      int n = t >> 5, i = t & 31;
      float4 v0 = *(const float4*)(shL + n*DD + i*4);
      float s = v0.x+v0.y+v0.z+v0.w;
      float q = v0.x*v0.x+v0.y*v0.y+v0.z*v0.z+v0.w*v0.w;
      #pragma unroll
      for (int m = 1; m < 32; m <<= 1) { s += __shfl_xor(s, m); q += __shfl_xor(q, m); }
      float mean = s*(1.f/128.f);
      float var  = q*(1.f/128.f) - mean*mean;
      float rs = rsqrtf(var + 1e-5f);
      union { h16 h[4]; uint2 u; } P;
      P.h[0] = (h16)((v0.x-mean)*rs); P.h[1] = (h16)((v0.y-mean)*rs);
      P.h[2] = (h16)((v0.z-mean)*rs); P.h[3] = (h16)((v0.w-mean)*rs);
      int row = 256 + n;
      *(uint2*)(nbcL + row*256 + ((i*8) ^ ((n&7)<<4))) = P.u;
      __syncthreads();
    }
  }

  // ---- final projection: out = h2 @ W_red^T + b_red (f32 output) ----
  {
    int n = t >> 5, z = t & 31;
    float acc0 = bred[z];
    #pragma unroll 8
    for (int e4 = 0; e4 < 32; ++e4) {
      float4 hv = *(const float4*)(shL + n*DD + e4*4);
      float4 wv = *(const float4*)(wred + z*DD + e4*4);
      acc0 += hv.x*wv.x + hv.y*wv.y + hv.z*wv.z + hv.w*wv.w;
    }
    out[(blk*16 + n)*32 + z] = acc0;
  }
}

// ---------------- launch ----------------
extern "C" void kernel_launch(void* const* d_in, const int* in_sizes, int n_in,
                              void* d_out, int out_size, void* d_ws, size_t ws_size,
                              hipStream_t stream) {
  (void)in_sizes; (void)n_in; (void)out_size; (void)ws_size;
  const float* x      = (const float*)d_in[0];
  const int*   edge   = (const int*)d_in[1];
  const float* coords = (const float*)d_in[2];
  const float* lg1v = (const float*)d_in[3];
  const float* lb1v = (const float*)d_in[4];
  const float* Ws1  = (const float*)d_in[5];
  const float* bs1  = (const float*)d_in[6];
  const float* Wn1  = (const float*)d_in[7];
  const float* bn1  = (const float*)d_in[8];
  const float* lg2v = (const float*)d_in[9];
  const float* lb2v = (const float*)d_in[10];
  const float* Ws2  = (const float*)d_in[11];
  const float* bs2  = (const float*)d_in[12];
  const float* Wn2  = (const float*)d_in[13];
  const float* bn2  = (const float*)d_in[14];
  const float* wred = (const float*)d_in[15];
  const float* bred = (const float*)d_in[16];

  h16* wsH = (h16*)d_ws;
  float* bpF = (float*)((char*)d_ws + 131072);

  FoldArgs fa;
  fa.W[0]=Ws1; fa.W[1]=Wn1; fa.W[2]=Ws2; fa.W[3]=Wn2;
  fa.g[0]=lg1v; fa.g[1]=lg1v; fa.g[2]=lg2v; fa.g[3]=lg2v;
  fa.bl[0]=lb1v; fa.bl[1]=lb1v; fa.bl[2]=lb2v; fa.bl[3]=lb2v;
  fa.bb[0]=bs1; fa.bb[1]=bn1; fa.bb[2]=bs2; fa.bb[3]=bn2;

  fold_kernel<<<512, 128, 0, stream>>>(fa, wsH, bpF);
  gae_main<<<1875, 512, 0, stream>>>(x, edge, coords, lg1v, lb1v, lg2v, lb2v,
      (const h16*)wsH, bpF, wred, bred, (float*)d_out);
}